// Round 11
// baseline (134.476 us; speedup 1.0000x reference)
//
#include <hip/hip_runtime.h>

// Problem constants (fixed by the reference).
#define BATCH 16384
#define DIN   128
#define HIDN  16
#define NNODE 255
#define NLEAF 256

typedef _Float16 half8 __attribute__((ext_vector_type(8)));
typedef float   float4v __attribute__((ext_vector_type(4)));

// ---------------- W1 pack kernel (255 blocks; x-pack inlined in k_fused) ----------
// block n packs W1[n] -> f16 A-operand fragments (LDS-staged):
//   lane L holds A[m=L&15][k=(L>>4)*8+j] (m=hidden, k=din)
__global__ __launch_bounds__(256) void k_packw(const float* __restrict__ w1, half8* __restrict__ w1p) {
    __shared__ float w[DIN * 17];
    int t = threadIdx.x;
    int n = blockIdx.x;
    const float4* src = (const float4*)(w1 + (size_t)n * (DIN * HIDN)) + t * 2;
    float4 a0 = src[0], a1 = src[1];
    int base = t * 8;
#pragma unroll
    for (int e = 0; e < 4; ++e) {
        int idx0 = base + e, idx1 = base + 4 + e;
        w[(idx0 >> 4) * 17 + (idx0 & 15)] = (&a0.x)[e];
        w[(idx1 >> 4) * 17 + (idx1 & 15)] = (&a1.x)[e];
    }
    __syncthreads();
    int L  = t & 63;
    int kc = t >> 6;
    int m  = L & 15;
    int k0 = kc * 32 + (L >> 4) * 8;
    half8 v;
#pragma unroll
    for (int j = 0; j < 8; ++j) v[j] = (_Float16)w[(k0 + j) * 17 + m];
    w1p[(size_t)n * 256 + t] = v;
}

// ---------------- fused MLP + tree kernel (MEASUREMENT ROUND) ----------------
// Structure identical to R10 except sp stride 260->261 (260%32==4 -> lanes 8 apart
// shared a bank: 8-way conflict on every phase-1 ds_write; 261%32==5, gcd(5,32)=1
// -> 2 lanes/bank = free).
// This round launches k_fused TWICE (idempotent: output is a pure function of
// inputs; dup writes are bitwise identical). Purpose: the kernel has sat just
// below the harness fills' 43-45 us for 5 rounds, so its counters (VGPR_Count,
// MfmaUtil, VALUBusy, SQ_LDS_BANK_CONFLICT) were never visible in top-5. The
// second dispatch surfaces them and Delta(total) gives its exact marginal cost.
__global__ __launch_bounds__(768, 3) void k_fused(const float* __restrict__ x, const half8* __restrict__ w1p,
                                                  const float* __restrict__ b1, const float* __restrict__ w2,
                                                  const float* __restrict__ b2, const float* __restrict__ leaf,
                                                  float* __restrict__ h_out, float* __restrict__ pp_out,
                                                  float* __restrict__ p_out, float* __restrict__ nr_out) {
    __shared__ float sp[64][261];                 // 65.3 KB, stride 261 (bank-friendly)
    __shared__ half8 xq[16][64];                  // 16 KB staged B-fragments
    int tid  = threadIdx.x;
    int wv   = tid >> 6;                          // 0..11
    int lane = tid & 63;
    int q    = lane >> 4;

    // ---- phase 0: inline x -> f16 fragment pack ----
    for (int g = tid; g < 1024; g += 768) {
        int f  = g >> 6, ln = g & 63;
        int t  = f >> 2, kc = f & 3;
        const float4* src = (const float4*)(x + (size_t)(blockIdx.x * 64 + t * 16 + (ln & 15)) * DIN
                                              + kc * 32 + ((ln >> 4) * 8));
        float4 v0 = src[0], v1 = src[1];
        half8 v;
        v[0] = (_Float16)v0.x; v[1] = (_Float16)v0.y; v[2] = (_Float16)v0.z; v[3] = (_Float16)v0.w;
        v[4] = (_Float16)v1.x; v[5] = (_Float16)v1.y; v[6] = (_Float16)v1.z; v[7] = (_Float16)v1.w;
        xq[f][ln] = v;
    }
    __syncthreads();

    half8 bq[4][4];
#pragma unroll
    for (int t = 0; t < 4; ++t)
#pragma unroll
        for (int kc = 0; kc < 4; ++kc)
            bq[t][kc] = xq[t * 4 + kc][lane];
    asm volatile("" ::: "memory");

    // ---- phase 1: MLP over this wave's nodes (n == wv mod 12), ping-pong ----
    half8  aA[4], aB[4];
    float4 b1A, b1B, w2A, w2B;
    float  b2A, b2B;

    int nA = wv;
#pragma unroll
    for (int kc = 0; kc < 4; ++kc) aA[kc] = w1p[(size_t)(nA * 4 + kc) * 64 + lane];
    b1A = ((const float4*)(b1 + nA * HIDN))[q];
    w2A = ((const float4*)(w2 + nA * HIDN))[q];
    b2A = b2[nA];
    {
        int nB = nA + 12;
#pragma unroll
        for (int kc = 0; kc < 4; ++kc) aB[kc] = w1p[(size_t)(nB * 4 + kc) * 64 + lane];
        b1B = ((const float4*)(b1 + nB * HIDN))[q];
        w2B = ((const float4*)(w2 + nB * HIDN))[q];
        b2B = b2[nB];
    }

// One node: 16 MFMA -> f32 relu-FMA partials -> prefetch -> butterfly -> sigmoid -> LDS.
// Butterfly: lane(q,b) ends with logit of tile t==q, batch row q*16+b == lane.
#define MLP_BODY(AS, B1S, W2S, B2S, NODE, PREN)                                            \
    do {                                                                                   \
        float4v acc0 = {B1S.x, B1S.y, B1S.z, B1S.w};                                       \
        float4v acc1 = acc0, acc2 = acc0, acc3 = acc0;                                     \
        _Pragma("unroll") for (int kc = 0; kc < 4; ++kc) {                                 \
            acc0 = __builtin_amdgcn_mfma_f32_16x16x32_f16(AS[kc], bq[0][kc], acc0, 0, 0, 0);\
            acc1 = __builtin_amdgcn_mfma_f32_16x16x32_f16(AS[kc], bq[1][kc], acc1, 0, 0, 0);\
            acc2 = __builtin_amdgcn_mfma_f32_16x16x32_f16(AS[kc], bq[2][kc], acc2, 0, 0, 0);\
            acc3 = __builtin_amdgcn_mfma_f32_16x16x32_f16(AS[kc], bq[3][kc], acc3, 0, 0, 0);\
        }                                                                                  \
        float s0 = fmaf(fmaxf(acc0[0], 0.f), W2S.x, fmaf(fmaxf(acc0[1], 0.f), W2S.y,       \
                   fmaf(fmaxf(acc0[2], 0.f), W2S.z, fmaxf(acc0[3], 0.f) * W2S.w)));        \
        float s1 = fmaf(fmaxf(acc1[0], 0.f), W2S.x, fmaf(fmaxf(acc1[1], 0.f), W2S.y,       \
                   fmaf(fmaxf(acc1[2], 0.f), W2S.z, fmaxf(acc1[3], 0.f) * W2S.w)));        \
        float s2 = fmaf(fmaxf(acc2[0], 0.f), W2S.x, fmaf(fmaxf(acc2[1], 0.f), W2S.y,       \
                   fmaf(fmaxf(acc2[2], 0.f), W2S.z, fmaxf(acc2[3], 0.f) * W2S.w)));        \
        float s3 = fmaf(fmaxf(acc3[0], 0.f), W2S.x, fmaf(fmaxf(acc3[1], 0.f), W2S.y,       \
                   fmaf(fmaxf(acc3[2], 0.f), W2S.z, fmaxf(acc3[3], 0.f) * W2S.w)));        \
        float b2c = B2S;                                                                   \
        _Pragma("unroll") for (int kc = 0; kc < 4; ++kc)                                   \
            AS[kc] = w1p[(size_t)((PREN) * 4 + kc) * 64 + lane];                           \
        B1S = ((const float4*)(b1 + (PREN) * HIDN))[q];                                    \
        W2S = ((const float4*)(w2 + (PREN) * HIDN))[q];                                    \
        B2S = b2[PREN];                                                                    \
        int q1 = q & 1, q2 = q & 2;                                                        \
        float a01 = q1 ? s1 : s0, c01 = q1 ? s0 : s1;                                      \
        a01 += __shfl_xor(c01, 16, 64);                                                    \
        float a23 = q1 ? s3 : s2, c23 = q1 ? s2 : s3;                                      \
        a23 += __shfl_xor(c23, 16, 64);                                                    \
        float e = q2 ? a23 : a01, f = q2 ? a01 : a23;                                      \
        e += __shfl_xor(f, 32, 64);                                                        \
        float lg = e + b2c;                                                                \
        sp[lane][NODE] =                                                                   \
            __builtin_amdgcn_rcpf(1.f + __builtin_amdgcn_exp2f(-1.44269504088896f * lg));  \
    } while (0)

    // 11 ping-pong iterations cover nodes {wv + 12j, j=0..21}; indices past 254
    // clamp to 254 (recomputed with node-254's own operands -> identical value).
    for (int ii = 0; ii < 11; ++ii) {
        int pA = nA + 24; pA = pA > 254 ? 254 : pA;
        MLP_BODY(aA, b1A, w2A, b2A, nA, pA);          // nA <= 252 always
        int nB = nA + 12; nB = nB > 254 ? 254 : nB;
        int pB = nA + 36; pB = pB > 254 ? 254 : pB;
        MLP_BODY(aB, b1B, w2B, b2B, nB, pB);
        nA += 24;
    }
#undef MLP_BODY
    __syncthreads();

    // ---- phase 2: tree scan, rows r = wv, wv+12, ... straight from LDS ----
    const float4 lf = *(const float4*)(leaf + 4 * lane);
    for (int r = wv; r < 64; r += 12) {
        int b = blockIdx.x * 64 + r;
        const float* P = &sp[r][0];
        float* nr = nr_out + (size_t)b * NNODE;

        // p_out copy, coalesced
#pragma unroll
        for (int c = 0; c < 4; ++c) {
            int idx = c * 64 + lane;
            if (idx < NNODE)
                p_out[(size_t)b * NNODE + idx] = P[idx];
        }

        float pref = 1.f;
#pragma unroll
        for (int l = 0; l < 6; ++l) {
            if ((lane & ((1 << (6 - l)) - 1)) == 0)
                nr[(1 << l) - 1 + (lane >> (6 - l))] = pref;
            float pv  = P[(1 << l) - 1 + (lane >> (6 - l))];
            int  bit  = (lane >> (5 - l)) & 1;
            pref *= bit ? pv : (1.f - pv);
        }
        nr[63 + lane] = pref;
        float p6 = P[63 + lane];
        float pl = pref * (1.f - p6);
        float pr = pref * p6;
        nr[127 + 2 * lane] = pl;
        nr[128 + 2 * lane] = pr;
        float p7a = P[127 + 2 * lane];
        float p7b = P[128 + 2 * lane];
        float4v pp;
        pp[0] = pl * (1.f - p7a);
        pp[1] = pl * p7a;
        pp[2] = pr * (1.f - p7b);
        pp[3] = pr * p7b;
        *(float4v*)(pp_out + (size_t)b * NLEAF + 4 * lane) = pp;
        float hs = pp[0] * lf.x + pp[1] * lf.y + pp[2] * lf.z + pp[3] * lf.w;
#pragma unroll
        for (int off = 1; off < 64; off <<= 1) hs += __shfl_xor(hs, off, 64);
        if (lane == 0) h_out[b] = hs;
    }
}

extern "C" void kernel_launch(void* const* d_in, const int* in_sizes, int n_in,
                              void* d_out, int out_size, void* d_ws, size_t ws_size,
                              hipStream_t stream) {
    const float* x    = (const float*)d_in[0];
    const float* W1   = (const float*)d_in[1];
    const float* b1   = (const float*)d_in[2];
    const float* W2   = (const float*)d_in[3];
    const float* b2   = (const float*)d_in[4];
    const float* leaf = (const float*)d_in[5];

    float* out    = (float*)d_out;
    float* h_out  = out;                                   // [16384]
    float* pp_out = out + BATCH;                           // [16384*256]
    float* p_out  = pp_out + (size_t)BATCH * NLEAF;        // [16384*255]
    float* nr_out = p_out + (size_t)BATCH * NNODE;         // [16384*255]

    // workspace: ~1 MB w1p only
    half8* w1p = (half8*)d_ws;

    hipLaunchKernelGGL(k_packw, dim3(NNODE), dim3(256), 0, stream, W1, w1p);
    // MEASUREMENT: two identical (idempotent) launches — the duplicate surfaces
    // k_fused in the rocprof top-5 with full counters and isolates its marginal cost.
    hipLaunchKernelGGL(k_fused, dim3(256),   dim3(768), 0, stream,
                       x, w1p, b1, W2, b2, leaf, h_out, pp_out, p_out, nr_out);
    hipLaunchKernelGGL(k_fused, dim3(256),   dim3(768), 0, stream,
                       x, w1p, b1, W2, b2, leaf, h_out, pp_out, p_out, nr_out);
}

// Round 13
// 116.719 us; speedup vs baseline: 1.1521x; 1.1521x over previous
//
#include <hip/hip_runtime.h>

// Problem constants (fixed by the reference).
#define BATCH 16384
#define DIN   128
#define HIDN  16
#define NNODE 255
#define NLEAF 256

typedef _Float16 half8 __attribute__((ext_vector_type(8)));
typedef float   float4v __attribute__((ext_vector_type(4)));

// ---------------- combined pack kernel (R8 structure — proven best) ----------------
// blocks 0..1023: pack x -> f16 B-operand fragments
//   lane L holds B[k=(L>>4)*8+j][n=L&15] (n=batch, k=din); ws: [bt][kc][lane] half8
// blocks 1024..1278: pack W1[n] -> f16 A-operand fragments (LDS-staged)
//   lane L holds A[m=L&15][k=(L>>4)*8+j] (m=hidden, k=din)
__global__ __launch_bounds__(256) void k_pack(const float* __restrict__ x, const float* __restrict__ w1,
                                              half8* __restrict__ xp, half8* __restrict__ w1p) {
    __shared__ float w[DIN * 17];
    int t = threadIdx.x;
    if (blockIdx.x < 1024) {
        int gid  = blockIdx.x * 256 + t;
        int lane = gid & 63;
        int kc   = (gid >> 6) & 3;
        int bt   = gid >> 8;
        const float4* src = (const float4*)(x + (size_t)(bt * 16 + (lane & 15)) * DIN + kc * 32 + ((lane >> 4) * 8));
        float4 v0 = src[0], v1 = src[1];
        half8 v;
        v[0] = (_Float16)v0.x; v[1] = (_Float16)v0.y; v[2] = (_Float16)v0.z; v[3] = (_Float16)v0.w;
        v[4] = (_Float16)v1.x; v[5] = (_Float16)v1.y; v[6] = (_Float16)v1.z; v[7] = (_Float16)v1.w;
        xp[gid] = v;
    } else {
        int n = blockIdx.x - 1024;
        const float4* src = (const float4*)(w1 + (size_t)n * (DIN * HIDN)) + t * 2;
        float4 a0 = src[0], a1 = src[1];
        int base = t * 8;
#pragma unroll
        for (int e = 0; e < 4; ++e) {
            int idx0 = base + e, idx1 = base + 4 + e;
            w[(idx0 >> 4) * 17 + (idx0 & 15)] = (&a0.x)[e];
            w[(idx1 >> 4) * 17 + (idx1 & 15)] = (&a1.x)[e];
        }
        __syncthreads();
        int L  = t & 63;
        int kc = t >> 6;
        int m  = L & 15;
        int k0 = kc * 32 + (L >> 4) * 8;
        half8 v;
#pragma unroll
        for (int j = 0; j < 8; ++j) v[j] = (_Float16)w[(k0 + j) * 17 + m];
        w1p[(size_t)n * 256 + t] = v;
    }
}

// ---------------- fused MLP + tree kernel, 64 rows / block, 12 waves ----------------
// Grid 256 (1/CU) x 768 thr (3 waves/SIMD). LDS sp[64][261] = 65.3 KB.
// R11 measurement: k_fused marginal = 26.3 us vs composite floor ~16-17 us; the gap
// is the strict phase split (compute-bound phase 1 leaves the store pipe idle,
// store-bound phase 2 leaves MFMA idle). This version moves the p_out write (1/3 of
// phase-2 store traffic) INTO phase 1: the butterfly leaves sigmoid with batch=lane,
// so each node stores its p_out column directly (1 store/node/wave — same instr
// count as the deleted phase-2 copy loop, but overlapped under MFMA; also deletes
// the phase-2 sp re-reads for the copy). Clamp-dup stores are bitwise identical.
__global__ __launch_bounds__(768, 3) void k_fused(const half8* __restrict__ xp, const half8* __restrict__ w1p,
                                                  const float* __restrict__ b1, const float* __restrict__ w2,
                                                  const float* __restrict__ b2, const float* __restrict__ leaf,
                                                  float* __restrict__ h_out, float* __restrict__ pp_out,
                                                  float* __restrict__ p_out, float* __restrict__ nr_out) {
    __shared__ float sp[64][261];                 // stride 261 (bank-clean, proven safe)
    int wv   = threadIdx.x >> 6;                  // 0..11
    int lane = threadIdx.x & 63;
    int q    = lane >> 4;
    int bt0  = blockIdx.x * 4;                    // four 16-row tiles

    // per-lane p_out base: this lane's batch row
    float* pout_lane = p_out + (size_t)(blockIdx.x * 64 + lane) * NNODE;

    // B-fragments for all 4 tiles (identical in every wave): 16 half8 = 64 VGPRs
    half8 bq[4][4];
#pragma unroll
    for (int t = 0; t < 4; ++t)
#pragma unroll
        for (int kc = 0; kc < 4; ++kc)
            bq[t][kc] = xp[(size_t)((bt0 + t) * 4 + kc) * 64 + lane];
    asm volatile("" ::: "memory");

    // ---- phase 1: MLP over this wave's nodes (n == wv mod 12), ping-pong ----
    half8  aA[4], aB[4];
    float4 b1A, b1B, w2A, w2B;
    float  b2A, b2B;

    int nA = wv;
#pragma unroll
    for (int kc = 0; kc < 4; ++kc) aA[kc] = w1p[(size_t)(nA * 4 + kc) * 64 + lane];
    b1A = ((const float4*)(b1 + nA * HIDN))[q];
    w2A = ((const float4*)(w2 + nA * HIDN))[q];
    b2A = b2[nA];
    {
        int nB = nA + 12;
#pragma unroll
        for (int kc = 0; kc < 4; ++kc) aB[kc] = w1p[(size_t)(nB * 4 + kc) * 64 + lane];
        b1B = ((const float4*)(b1 + nB * HIDN))[q];
        w2B = ((const float4*)(w2 + nB * HIDN))[q];
        b2B = b2[nB];
    }

// One node: 16 MFMA -> f32 relu-FMA partials -> prefetch -> butterfly -> sigmoid
// -> LDS store (for tree scan) + direct p_out store (overlapped output write).
// Butterfly: lane(q,b) ends with logit of tile t==q, batch row q*16+b == lane.
#define MLP_BODY(AS, B1S, W2S, B2S, NODE, PREN)                                            \
    do {                                                                                   \
        float4v acc0 = {B1S.x, B1S.y, B1S.z, B1S.w};                                       \
        float4v acc1 = acc0, acc2 = acc0, acc3 = acc0;                                     \
        _Pragma("unroll") for (int kc = 0; kc < 4; ++kc) {                                 \
            acc0 = __builtin_amdgcn_mfma_f32_16x16x32_f16(AS[kc], bq[0][kc], acc0, 0, 0, 0);\
            acc1 = __builtin_amdgcn_mfma_f32_16x16x32_f16(AS[kc], bq[1][kc], acc1, 0, 0, 0);\
            acc2 = __builtin_amdgcn_mfma_f32_16x16x32_f16(AS[kc], bq[2][kc], acc2, 0, 0, 0);\
            acc3 = __builtin_amdgcn_mfma_f32_16x16x32_f16(AS[kc], bq[3][kc], acc3, 0, 0, 0);\
        }                                                                                  \
        float s0 = fmaf(fmaxf(acc0[0], 0.f), W2S.x, fmaf(fmaxf(acc0[1], 0.f), W2S.y,       \
                   fmaf(fmaxf(acc0[2], 0.f), W2S.z, fmaxf(acc0[3], 0.f) * W2S.w)));        \
        float s1 = fmaf(fmaxf(acc1[0], 0.f), W2S.x, fmaf(fmaxf(acc1[1], 0.f), W2S.y,       \
                   fmaf(fmaxf(acc1[2], 0.f), W2S.z, fmaxf(acc1[3], 0.f) * W2S.w)));        \
        float s2 = fmaf(fmaxf(acc2[0], 0.f), W2S.x, fmaf(fmaxf(acc2[1], 0.f), W2S.y,       \
                   fmaf(fmaxf(acc2[2], 0.f), W2S.z, fmaxf(acc2[3], 0.f) * W2S.w)));        \
        float s3 = fmaf(fmaxf(acc3[0], 0.f), W2S.x, fmaf(fmaxf(acc3[1], 0.f), W2S.y,       \
                   fmaf(fmaxf(acc3[2], 0.f), W2S.z, fmaxf(acc3[3], 0.f) * W2S.w)));        \
        float b2c = B2S;                                                                   \
        _Pragma("unroll") for (int kc = 0; kc < 4; ++kc)                                   \
            AS[kc] = w1p[(size_t)((PREN) * 4 + kc) * 64 + lane];                           \
        B1S = ((const float4*)(b1 + (PREN) * HIDN))[q];                                    \
        W2S = ((const float4*)(w2 + (PREN) * HIDN))[q];                                    \
        B2S = b2[PREN];                                                                    \
        int q1 = q & 1, q2 = q & 2;                                                        \
        float a01 = q1 ? s1 : s0, c01 = q1 ? s0 : s1;                                      \
        a01 += __shfl_xor(c01, 16, 64);                                                    \
        float a23 = q1 ? s3 : s2, c23 = q1 ? s2 : s3;                                      \
        a23 += __shfl_xor(c23, 16, 64);                                                    \
        float e = q2 ? a23 : a01, f = q2 ? a01 : a23;                                      \
        e += __shfl_xor(f, 32, 64);                                                        \
        float sg = __builtin_amdgcn_rcpf(1.f +                                             \
                   __builtin_amdgcn_exp2f(-1.44269504088896f * (e + b2c)));                \
        sp[lane][NODE] = sg;                                                               \
        pout_lane[NODE] = sg;                                                              \
    } while (0)

    // 11 ping-pong iterations cover nodes {wv + 12j, j=0..21}; indices past 254
    // clamp to 254 (recomputed with node-254's own operands -> identical value).
    for (int ii = 0; ii < 11; ++ii) {
        int pA = nA + 24; pA = pA > 254 ? 254 : pA;
        MLP_BODY(aA, b1A, w2A, b2A, nA, pA);          // nA <= 252 always
        int nB = nA + 12; nB = nB > 254 ? 254 : nB;
        int pB = nA + 36; pB = pB > 254 ? 254 : pB;
        MLP_BODY(aB, b1B, w2B, b2B, nB, pB);
        nA += 24;
    }
#undef MLP_BODY
    __syncthreads();

    // ---- phase 2: tree scan, rows r = wv, wv+12, ... straight from LDS ----
    // (p_out already written in phase 1)
    const float4 lf = *(const float4*)(leaf + 4 * lane);
    for (int r = wv; r < 64; r += 12) {
        int b = blockIdx.x * 64 + r;
        const float* P = &sp[r][0];
        float* nr = nr_out + (size_t)b * NNODE;

        float pref = 1.f;
#pragma unroll
        for (int l = 0; l < 6; ++l) {
            if ((lane & ((1 << (6 - l)) - 1)) == 0)
                nr[(1 << l) - 1 + (lane >> (6 - l))] = pref;
            float pv  = P[(1 << l) - 1 + (lane >> (6 - l))];
            int  bit  = (lane >> (5 - l)) & 1;
            pref *= bit ? pv : (1.f - pv);
        }
        nr[63 + lane] = pref;
        float p6 = P[63 + lane];
        float pl = pref * (1.f - p6);
        float pr = pref * p6;
        nr[127 + 2 * lane] = pl;
        nr[128 + 2 * lane] = pr;
        float p7a = P[127 + 2 * lane];
        float p7b = P[128 + 2 * lane];
        float4v pp;
        pp[0] = pl * (1.f - p7a);
        pp[1] = pl * p7a;
        pp[2] = pr * (1.f - p7b);
        pp[3] = pr * p7b;
        *(float4v*)(pp_out + (size_t)b * NLEAF + 4 * lane) = pp;
        float hs = pp[0] * lf.x + pp[1] * lf.y + pp[2] * lf.z + pp[3] * lf.w;
#pragma unroll
        for (int off = 1; off < 64; off <<= 1) hs += __shfl_xor(hs, off, 64);
        if (lane == 0) h_out[b] = hs;
    }
}

extern "C" void kernel_launch(void* const* d_in, const int* in_sizes, int n_in,
                              void* d_out, int out_size, void* d_ws, size_t ws_size,
                              hipStream_t stream) {
    const float* x    = (const float*)d_in[0];
    const float* W1   = (const float*)d_in[1];
    const float* b1   = (const float*)d_in[2];
    const float* W2   = (const float*)d_in[3];
    const float* b2   = (const float*)d_in[4];
    const float* leaf = (const float*)d_in[5];

    float* out    = (float*)d_out;
    float* h_out  = out;                                   // [16384]
    float* pp_out = out + BATCH;                           // [16384*256]
    float* p_out  = pp_out + (size_t)BATCH * NLEAF;        // [16384*255]
    float* nr_out = p_out + (size_t)BATCH * NNODE;         // [16384*255]

    // workspace: 4 MB xp + ~1 MB w1p
    half8* xp  = (half8*)d_ws;
    half8* w1p = xp + (size_t)1024 * 4 * 64;

    hipLaunchKernelGGL(k_pack,  dim3(1024 + NNODE), dim3(256), 0, stream, x, W1, xp, w1p);
    hipLaunchKernelGGL(k_fused, dim3(256),          dim3(768), 0, stream,
                       xp, w1p, b1, W2, b2, leaf, h_out, pp_out, p_out, nr_out);
}

// Round 14
// 108.563 us; speedup vs baseline: 1.2387x; 1.0751x over previous
//
#include <hip/hip_runtime.h>

// Problem constants (fixed by the reference).
#define BATCH 16384
#define DIN   128
#define HIDN  16
#define NNODE 255
#define NPAD  288          // padded node count: clamp-free phase-1 loop
#define NLEAF 256

typedef _Float16 half8 __attribute__((ext_vector_type(8)));
typedef float   float4v __attribute__((ext_vector_type(4)));

// ---------------- combined pack kernel ----------------
// blocks 0..1023: pack x -> f16 B-operand fragments (R8-proven path)
// blocks 1024..1311: node n = blk-1024 (0..287):
//   n < 255: pack W1[n] -> f16 A-fragments (LDS-staged) + copy b1/w2/b2 rows
//            into padded arrays
//   n >= 255: zero-fill pad entries (so unclamped loads read benign zeros)
__global__ __launch_bounds__(256) void k_pack(const float* __restrict__ x, const float* __restrict__ w1,
                                              const float* __restrict__ b1, const float* __restrict__ w2,
                                              const float* __restrict__ b2,
                                              half8* __restrict__ xp, half8* __restrict__ w1p,
                                              float* __restrict__ b1q, float* __restrict__ w2q,
                                              float* __restrict__ b2q) {
    __shared__ float w[DIN * 17];
    int t = threadIdx.x;
    if (blockIdx.x < 1024) {
        int gid  = blockIdx.x * 256 + t;
        int lane = gid & 63;
        int kc   = (gid >> 6) & 3;
        int bt   = gid >> 8;
        const float4* src = (const float4*)(x + (size_t)(bt * 16 + (lane & 15)) * DIN + kc * 32 + ((lane >> 4) * 8));
        float4 v0 = src[0], v1 = src[1];
        half8 v;
        v[0] = (_Float16)v0.x; v[1] = (_Float16)v0.y; v[2] = (_Float16)v0.z; v[3] = (_Float16)v0.w;
        v[4] = (_Float16)v1.x; v[5] = (_Float16)v1.y; v[6] = (_Float16)v1.z; v[7] = (_Float16)v1.w;
        xp[gid] = v;
    } else {
        int n = blockIdx.x - 1024;
        if (n < NNODE) {
            const float4* src = (const float4*)(w1 + (size_t)n * (DIN * HIDN)) + t * 2;
            float4 a0 = src[0], a1 = src[1];
            int base = t * 8;
#pragma unroll
            for (int e = 0; e < 4; ++e) {
                int idx0 = base + e, idx1 = base + 4 + e;
                w[(idx0 >> 4) * 17 + (idx0 & 15)] = (&a0.x)[e];
                w[(idx1 >> 4) * 17 + (idx1 & 15)] = (&a1.x)[e];
            }
            __syncthreads();
            int L  = t & 63;
            int kc = t >> 6;
            int m  = L & 15;
            int k0 = kc * 32 + (L >> 4) * 8;
            half8 v;
#pragma unroll
            for (int j = 0; j < 8; ++j) v[j] = (_Float16)w[(k0 + j) * 17 + m];
            w1p[(size_t)n * 256 + t] = v;
            if (t < HIDN) {
                b1q[n * HIDN + t] = b1[n * HIDN + t];
                w2q[n * HIDN + t] = w2[n * HIDN + t];
            }
            if (t == 32) b2q[n] = b2[n];
        } else {
            half8 z = {};
            w1p[(size_t)n * 256 + t] = z;
            if (t < HIDN) { b1q[n * HIDN + t] = 0.f; w2q[n * HIDN + t] = 0.f; }
            if (t == 32) b2q[n] = 0.f;
        }
    }
}

// ---------------- fused MLP + tree kernel, 64 rows / block, 12 waves ----------------
// Grid 256 (1/CU) x 768 thr (3 waves/SIMD). LDS sp[64][261] = 65.3 KB.
// R13 counters: VALUBusy 25.5% (11.3 us) ~4x the hand-count -> address math bloat;
// the >254 clamps made every load index data-dependent, blocking strength
// reduction. This version: operand buffers padded to 288 nodes -> clamp-free
// constant-stride loop; dup/pad bodies store to trash column 255 of sp (never
// read; benign last-wins race). p_out write REVERTED to phase-2 coalesced copy
// (R13: scattered phase-1 stores amplified WRITE 50->82 MB, +5 us).
__global__ __launch_bounds__(768, 3) void k_fused(const half8* __restrict__ xp, const half8* __restrict__ w1p,
                                                  const float* __restrict__ b1q, const float* __restrict__ w2q,
                                                  const float* __restrict__ b2q, const float* __restrict__ leaf,
                                                  float* __restrict__ h_out, float* __restrict__ pp_out,
                                                  float* __restrict__ p_out, float* __restrict__ nr_out) {
    __shared__ float sp[64][261];                 // cols 0..254 real, 255 trash
    int wv   = threadIdx.x >> 6;                  // 0..11
    int lane = threadIdx.x & 63;
    int q    = lane >> 4;
    int bt0  = blockIdx.x * 4;                    // four 16-row tiles

    // B-fragments for all 4 tiles (identical in every wave): 16 half8 = 64 VGPRs
    half8 bq[4][4];
#pragma unroll
    for (int t = 0; t < 4; ++t)
#pragma unroll
        for (int kc = 0; kc < 4; ++kc)
            bq[t][kc] = xp[(size_t)((bt0 + t) * 4 + kc) * 64 + lane];
    asm volatile("" ::: "memory");

    // ---- phase 1: MLP over this wave's nodes (n == wv mod 12), ping-pong ----
    // Slots j=0..21, node = wv + 12j (<= 263 < 288: always in padded range).
    // Prefetch distance 2 slots; prefetch index max = wv + 276 <= 287.
    half8  aA[4], aB[4];
    float4 b1A, b1B, w2A, w2B;
    float  b2A, b2B;

    int nA = wv;
#pragma unroll
    for (int kc = 0; kc < 4; ++kc) aA[kc] = w1p[(size_t)(nA * 4 + kc) * 64 + lane];
    b1A = ((const float4*)(b1q + nA * HIDN))[q];
    w2A = ((const float4*)(w2q + nA * HIDN))[q];
    b2A = b2q[nA];
    {
        int nB = nA + 12;
#pragma unroll
        for (int kc = 0; kc < 4; ++kc) aB[kc] = w1p[(size_t)(nB * 4 + kc) * 64 + lane];
        b1B = ((const float4*)(b1q + nB * HIDN))[q];
        w2B = ((const float4*)(w2q + nB * HIDN))[q];
        b2B = b2q[nB];
    }

// One node: 16 MFMA -> f32 relu-FMA partials -> prefetch (UNCLAMPED, constant
// stride) -> butterfly -> sigmoid -> LDS store at col=min(node,255).
// Butterfly: lane(q,b) ends with logit of tile t==q, batch row q*16+b == lane.
#define MLP_BODY(AS, B1S, W2S, B2S, NODE, PREN)                                            \
    do {                                                                                   \
        float4v acc0 = {B1S.x, B1S.y, B1S.z, B1S.w};                                       \
        float4v acc1 = acc0, acc2 = acc0, acc3 = acc0;                                     \
        _Pragma("unroll") for (int kc = 0; kc < 4; ++kc) {                                 \
            acc0 = __builtin_amdgcn_mfma_f32_16x16x32_f16(AS[kc], bq[0][kc], acc0, 0, 0, 0);\
            acc1 = __builtin_amdgcn_mfma_f32_16x16x32_f16(AS[kc], bq[1][kc], acc1, 0, 0, 0);\
            acc2 = __builtin_amdgcn_mfma_f32_16x16x32_f16(AS[kc], bq[2][kc], acc2, 0, 0, 0);\
            acc3 = __builtin_amdgcn_mfma_f32_16x16x32_f16(AS[kc], bq[3][kc], acc3, 0, 0, 0);\
        }                                                                                  \
        float s0 = fmaf(fmaxf(acc0[0], 0.f), W2S.x, fmaf(fmaxf(acc0[1], 0.f), W2S.y,       \
                   fmaf(fmaxf(acc0[2], 0.f), W2S.z, fmaxf(acc0[3], 0.f) * W2S.w)));        \
        float s1 = fmaf(fmaxf(acc1[0], 0.f), W2S.x, fmaf(fmaxf(acc1[1], 0.f), W2S.y,       \
                   fmaf(fmaxf(acc1[2], 0.f), W2S.z, fmaxf(acc1[3], 0.f) * W2S.w)));        \
        float s2 = fmaf(fmaxf(acc2[0], 0.f), W2S.x, fmaf(fmaxf(acc2[1], 0.f), W2S.y,       \
                   fmaf(fmaxf(acc2[2], 0.f), W2S.z, fmaxf(acc2[3], 0.f) * W2S.w)));        \
        float s3 = fmaf(fmaxf(acc3[0], 0.f), W2S.x, fmaf(fmaxf(acc3[1], 0.f), W2S.y,       \
                   fmaf(fmaxf(acc3[2], 0.f), W2S.z, fmaxf(acc3[3], 0.f) * W2S.w)));        \
        float b2c = B2S;                                                                   \
        _Pragma("unroll") for (int kc = 0; kc < 4; ++kc)                                   \
            AS[kc] = w1p[(size_t)((PREN) * 4 + kc) * 64 + lane];                           \
        B1S = ((const float4*)(b1q + (PREN) * HIDN))[q];                                   \
        W2S = ((const float4*)(w2q + (PREN) * HIDN))[q];                                   \
        B2S = b2q[PREN];                                                                   \
        int q1 = q & 1, q2 = q & 2;                                                        \
        float a01 = q1 ? s1 : s0, c01 = q1 ? s0 : s1;                                      \
        a01 += __shfl_xor(c01, 16, 64);                                                    \
        float a23 = q1 ? s3 : s2, c23 = q1 ? s2 : s3;                                      \
        a23 += __shfl_xor(c23, 16, 64);                                                    \
        float e = q2 ? a23 : a01, f = q2 ? a01 : a23;                                      \
        e += __shfl_xor(f, 32, 64);                                                        \
        int col = (NODE) > 255 ? 255 : (NODE);                                             \
        sp[lane][col] = __builtin_amdgcn_rcpf(1.f +                                        \
                        __builtin_amdgcn_exp2f(-1.44269504088896f * (e + b2c)));           \
    } while (0)

    for (int ii = 0; ii < 11; ++ii) {
        MLP_BODY(aA, b1A, w2A, b2A, nA,      nA + 24);     // node wv+24ii,    pre wv+24ii+24
        MLP_BODY(aB, b1B, w2B, b2B, nA + 12, nA + 36);     // node wv+24ii+12, pre wv+24ii+36
        nA += 24;                                          // max prefetch: wv+276 <= 287
    }
#undef MLP_BODY
    __syncthreads();

    // ---- phase 2: tree scan, rows r = wv, wv+12, ... straight from LDS ----
    const float4 lf = *(const float4*)(leaf + 4 * lane);
    for (int r = wv; r < 64; r += 12) {
        int b = blockIdx.x * 64 + r;
        const float* P = &sp[r][0];
        float* nr = nr_out + (size_t)b * NNODE;

        // p_out copy, coalesced (reverted from scattered phase-1 stores)
#pragma unroll
        for (int c = 0; c < 4; ++c) {
            int idx = c * 64 + lane;
            if (idx < NNODE)
                p_out[(size_t)b * NNODE + idx] = P[idx];
        }

        float pref = 1.f;
#pragma unroll
        for (int l = 0; l < 6; ++l) {
            if ((lane & ((1 << (6 - l)) - 1)) == 0)
                nr[(1 << l) - 1 + (lane >> (6 - l))] = pref;
            float pv  = P[(1 << l) - 1 + (lane >> (6 - l))];
            int  bit  = (lane >> (5 - l)) & 1;
            pref *= bit ? pv : (1.f - pv);
        }
        nr[63 + lane] = pref;
        float p6 = P[63 + lane];
        float pl = pref * (1.f - p6);
        float pr = pref * p6;
        nr[127 + 2 * lane] = pl;
        nr[128 + 2 * lane] = pr;
        float p7a = P[127 + 2 * lane];
        float p7b = P[128 + 2 * lane];
        float4v pp;
        pp[0] = pl * (1.f - p7a);
        pp[1] = pl * p7a;
        pp[2] = pr * (1.f - p7b);
        pp[3] = pr * p7b;
        *(float4v*)(pp_out + (size_t)b * NLEAF + 4 * lane) = pp;
        float hs = pp[0] * lf.x + pp[1] * lf.y + pp[2] * lf.z + pp[3] * lf.w;
#pragma unroll
        for (int off = 1; off < 64; off <<= 1) hs += __shfl_xor(hs, off, 64);
        if (lane == 0) h_out[b] = hs;
    }
}

extern "C" void kernel_launch(void* const* d_in, const int* in_sizes, int n_in,
                              void* d_out, int out_size, void* d_ws, size_t ws_size,
                              hipStream_t stream) {
    const float* x    = (const float*)d_in[0];
    const float* W1   = (const float*)d_in[1];
    const float* b1   = (const float*)d_in[2];
    const float* W2   = (const float*)d_in[3];
    const float* b2   = (const float*)d_in[4];
    const float* leaf = (const float*)d_in[5];

    float* out    = (float*)d_out;
    float* h_out  = out;                                   // [16384]
    float* pp_out = out + BATCH;                           // [16384*256]
    float* p_out  = pp_out + (size_t)BATCH * NLEAF;        // [16384*255]
    float* nr_out = p_out + (size_t)BATCH * NNODE;         // [16384*255]

    // workspace: 4 MB xp + 1.18 MB w1p(288) + padded b1/w2/b2 copies
    half8* xp  = (half8*)d_ws;
    half8* w1p = xp + (size_t)1024 * 4 * 64;               // 288*256 half8s
    float* b1q = (float*)(w1p + (size_t)NPAD * 256);       // 288*16
    float* w2q = b1q + NPAD * HIDN;                        // 288*16
    float* b2q = w2q + NPAD * HIDN;                        // 288

    hipLaunchKernelGGL(k_pack,  dim3(1024 + NPAD), dim3(256), 0, stream,
                       x, W1, b1, W2, b2, xp, w1p, b1q, w2q, b2q);
    hipLaunchKernelGGL(k_fused, dim3(256),         dim3(768), 0, stream,
                       xp, w1p, b1q, w2q, b2q, leaf, h_out, pp_out, p_out, nr_out);
}